// Round 1
// baseline (270.950 us; speedup 1.0000x reference)
//
#include <hip/hip_runtime.h>
#include <hip/hip_bf16.h>
#include <math.h>

// ---------------------------------------------------------------------------
// Kernel 1: cost matrix.
// cost[b][q][g] = -( 1.0*c_rel + 0.5*(c_hs+c_he) + 0.5*(c_ts+c_te) )
// where c = softmax(row) L2-normalized, gathered at gold index.
// One block (256 threads = 4 waves) per (b,q) row; processes 5 tensors.
// ---------------------------------------------------------------------------

__device__ __forceinline__ float block_reduce(float val, bool do_max, float* sm) {
  #pragma unroll
  for (int o = 32; o > 0; o >>= 1) {
    float other = __shfl_xor(val, o);
    val = do_max ? fmaxf(val, other) : (val + other);
  }
  __syncthreads();                       // protect sm from previous call's readers
  if ((threadIdx.x & 63) == 0) sm[threadIdx.x >> 6] = val;
  __syncthreads();
  float r = do_max ? fmaxf(fmaxf(sm[0], sm[1]), fmaxf(sm[2], sm[3]))
                   : ((sm[0] + sm[1]) + (sm[2] + sm[3]));
  return r;
}

__global__ __launch_bounds__(256) void cost_kernel(
    const float* __restrict__ rel,
    const float* __restrict__ hs, const float* __restrict__ he,
    const float* __restrict__ ts, const float* __restrict__ te,
    const int* __restrict__ grel,
    const int* __restrict__ ghs, const int* __restrict__ ghe,
    const int* __restrict__ gts, const int* __restrict__ gte,
    float* __restrict__ cost)
{
  __shared__ float sm[4];
  const int bq  = blockIdx.x;        // b*512 + q
  const int b   = bq >> 9;
  const int tid = threadIdx.x;
  float acc = 0.0f;                  // meaningful for tid < 32

  #pragma unroll
  for (int t = 0; t < 5; ++t) {
    const float* row; const int* gold; int D; float w;
    switch (t) {
      case 0:  row = rel + (size_t)bq * 512;  gold = grel; D = 512;  w = 1.0f; break;
      case 1:  row = hs  + (size_t)bq * 1024; gold = ghs;  D = 1024; w = 0.5f; break;
      case 2:  row = he  + (size_t)bq * 1024; gold = ghe;  D = 1024; w = 0.5f; break;
      case 3:  row = ts  + (size_t)bq * 1024; gold = gts;  D = 1024; w = 0.5f; break;
      default: row = te  + (size_t)bq * 1024; gold = gte;  D = 1024; w = 0.5f; break;
    }
    const int nk = D >> 8;           // 2 or 4 elements per thread
    float x[4];
    float lmax = -INFINITY;
    #pragma unroll
    for (int k = 0; k < 4; ++k) if (k < nk) {
      float v = row[tid + (k << 8)];
      if (isnan(v)) v = -1e9f;
      x[k] = v;
      lmax = fmaxf(lmax, v);
    }
    float mx = block_reduce(lmax, true, sm);

    float lsum = 0.0f;
    #pragma unroll
    for (int k = 0; k < 4; ++k) if (k < nk) { x[k] = expf(x[k] - mx); lsum += x[k]; }
    float S = block_reduce(lsum, false, sm);

    float lss = 0.0f;
    #pragma unroll
    for (int k = 0; k < 4; ++k) if (k < nk) { float pk = x[k] / S; lss += pk * pk; }
    float ssq = block_reduce(lss, false, sm);
    float denom = fmaxf(sqrtf(ssq), 1e-12f);

    if (tid < 32) {
      int idx = gold[(b << 5) + tid];
      float xg = row[idx];
      if (isnan(xg)) xg = -1e9f;
      float pg = expf(xg - mx) / S;
      acc += w * (pg / denom);
    }
  }
  if (tid < 32) cost[(size_t)bq * 32 + tid] = -acc;
}

// ---------------------------------------------------------------------------
// Kernel 2: faithful replica of the reference's (buggy) JV loop.
// Key facts proven from the reference source: minv stays INF (mv/wy are
// copies never written back) => delta == +INF always; way stays all-zero =>
// augmentation is exactly p[j_final] = i. u in {0,+inf}, v in {0,-inf}.
// All comparisons are between exact fp32 cost values and +-inf/NaN, so fp32
// reproduces the fp64 numpy behavior bit-for-bit (incl. first-index argmin
// tie-break). One wave per batch.
// ---------------------------------------------------------------------------

__global__ __launch_bounds__(64) void hungarian_kernel(
    const float* __restrict__ cost, float* __restrict__ out)
{
  __shared__ float v[513];
  __shared__ float u[33];
  __shared__ int   p[513];
  __shared__ int   stamp[513];   // stamp[j] == i  <=>  used[j] this turn

  const int b    = blockIdx.x;
  const int lane = threadIdx.x;
  const float* cb = cost + (size_t)b * 512 * 32;
  const float INFV = __builtin_inff();

  for (int j = lane; j < 513; j += 64) { v[j] = 0.0f; p[j] = 0; stamp[j] = -1; }
  if (lane < 33) u[lane] = 0.0f;
  __syncthreads();

  for (int i = 1; i <= 32; ++i) {
    if (lane == 0) p[0] = i;
    __syncthreads();
    int j0 = 0;
    for (int guard = 0; guard < 1024; ++guard) {
      int   i0  = p[j0];           // uniform LDS reads (pre-update values)
      float ui0 = u[i0];
      __syncthreads();
      if (lane == 0) { stamp[j0] = i; u[i0] = INFV; v[j0] = -INFV; }
      __syncthreads();

      // argmin over free j of mv_j = (cur_j < INF ? cur_j : INF), first index wins.
      // When ui0 == +inf the cost term is irrelevant (x - inf = -inf for any
      // finite x), so skip the global read.
      float best = INFV; int bj = 0x7fffffff;
      const bool finite_u = (ui0 < INFV);
      #pragma unroll
      for (int k = 0; k < 8; ++k) {
        int j = 1 + lane + (k << 6);
        if (stamp[j] != i) {
          float ct  = finite_u ? cb[(size_t)(j - 1) * 32 + (i0 - 1)] : 0.0f;
          float cur = ct - ui0 - v[j];            // fp32 inf/NaN == fp64 inf/NaN
          float key = (cur < INFV) ? cur : INFV;  // NaN -> INF (matches numpy mask)
          if (key < best || (key == best && j < bj)) { best = key; bj = j; }
        }
      }
      #pragma unroll
      for (int off = 32; off > 0; off >>= 1) {
        float ob = __shfl_xor(best, off);
        int   oj = __shfl_xor(bj, off);
        if (ob < best || (ob == best && oj < bj)) { best = ob; bj = oj; }
      }
      j0 = bj;
      if (j0 > 512) break;         // safety: cannot happen (free columns remain)
      if (p[j0] == 0) break;       // found an unassigned column
    }
    __syncthreads();
    if (lane == 0) p[j0] = i;      // augmentation with way == 0 collapses to this
    __syncthreads();
  }

  if (lane == 0) {
    int rows[32];
    for (int j = 1; j <= 512; ++j) { int pi = p[j]; if (pi > 0) rows[pi - 1] = j - 1; }
    int ord[32];
    for (int g = 0; g < 32; ++g) ord[g] = g;
    for (int a = 0; a < 31; ++a) {         // argsort(rows), values distinct
      int mb = a;
      for (int c = a + 1; c < 32; ++c) if (rows[ord[c]] < rows[ord[mb]]) mb = c;
      int tmp = ord[a]; ord[a] = ord[mb]; ord[mb] = tmp;
    }
    float* orow = out + 131072;
    float* ocol = out + 131072 + 256;
    for (int k = 0; k < 32; ++k) {
      orow[b * 32 + k] = (float)rows[ord[k]];
      ocol[b * 32 + k] = (float)ord[k];
    }
  }
}

// ---------------------------------------------------------------------------

extern "C" void kernel_launch(void* const* d_in, const int* in_sizes, int n_in,
                              void* d_out, int out_size, void* d_ws, size_t ws_size,
                              hipStream_t stream) {
  const float* rel = (const float*)d_in[0];
  const float* hs  = (const float*)d_in[1];
  const float* he  = (const float*)d_in[2];
  const float* ts  = (const float*)d_in[3];
  const float* te  = (const float*)d_in[4];
  const int* grel = (const int*)d_in[5];
  const int* ghs  = (const int*)d_in[6];
  const int* ghe  = (const int*)d_in[7];
  const int* gts  = (const int*)d_in[8];
  const int* gte  = (const int*)d_in[9];

  float* out  = (float*)d_out;
  float* cost = out;   // [8,512,32] -> first 131072 floats

  cost_kernel<<<8 * 512, 256, 0, stream>>>(rel, hs, he, ts, te,
                                           grel, ghs, ghe, gts, gte, cost);
  hungarian_kernel<<<8, 64, 0, stream>>>(cost, out);
}

// Round 2
// 95.973 us; speedup vs baseline: 2.8232x; 2.8232x over previous
//
#include <hip/hip_runtime.h>
#include <hip/hip_bf16.h>
#include <math.h>

// ---------------------------------------------------------------------------
// Kernel 1: cost matrix.
// cost[b][q][g] = -( 1.0*c_rel + 0.5*(c_hs+c_he) + 0.5*(c_ts+c_te) )
// where c = softmax(row) L2-normalized, gathered at gold index.
// One block (256 threads = 4 waves) per (b,q) row; 5 tensors per block.
// Loads vectorized: float4 (D=1024) / float2 (D=512) per lane.
// ---------------------------------------------------------------------------

__device__ __forceinline__ float block_reduce(float val, bool do_max, float* sm) {
  #pragma unroll
  for (int o = 32; o > 0; o >>= 1) {
    float other = __shfl_xor(val, o);
    val = do_max ? fmaxf(val, other) : (val + other);
  }
  __syncthreads();                       // protect sm from previous call's readers
  if ((threadIdx.x & 63) == 0) sm[threadIdx.x >> 6] = val;
  __syncthreads();
  float r = do_max ? fmaxf(fmaxf(sm[0], sm[1]), fmaxf(sm[2], sm[3]))
                   : ((sm[0] + sm[1]) + (sm[2] + sm[3]));
  return r;
}

__global__ __launch_bounds__(256) void cost_kernel(
    const float* __restrict__ rel,
    const float* __restrict__ hs, const float* __restrict__ he,
    const float* __restrict__ ts, const float* __restrict__ te,
    const int* __restrict__ grel,
    const int* __restrict__ ghs, const int* __restrict__ ghe,
    const int* __restrict__ gts, const int* __restrict__ gte,
    float* __restrict__ cost)
{
  __shared__ float sm[4];
  const int bq  = blockIdx.x;        // b*512 + q
  const int b   = bq >> 9;
  const int tid = threadIdx.x;
  float acc = 0.0f;                  // meaningful for tid < 32

  #pragma unroll
  for (int t = 0; t < 5; ++t) {
    const float* row; const int* gold; int nk; float w;
    switch (t) {
      case 0:  row = rel + (size_t)bq * 512;  gold = grel; nk = 2; w = 1.0f; break;
      case 1:  row = hs  + (size_t)bq * 1024; gold = ghs;  nk = 4; w = 0.5f; break;
      case 2:  row = he  + (size_t)bq * 1024; gold = ghe;  nk = 4; w = 0.5f; break;
      case 3:  row = ts  + (size_t)bq * 1024; gold = gts;  nk = 4; w = 0.5f; break;
      default: row = te  + (size_t)bq * 1024; gold = gte;  nk = 4; w = 0.5f; break;
    }
    // contiguous chunk of nk floats per lane, vector load
    float x[4];
    if (nk == 4) {
      float4 v4 = *reinterpret_cast<const float4*>(row + tid * 4);
      x[0] = v4.x; x[1] = v4.y; x[2] = v4.z; x[3] = v4.w;
    } else {
      float2 v2 = *reinterpret_cast<const float2*>(row + tid * 2);
      x[0] = v2.x; x[1] = v2.y; x[2] = 0.0f; x[3] = 0.0f;
    }
    float lmax = -INFINITY;
    #pragma unroll
    for (int k = 0; k < 4; ++k) if (k < nk) {
      if (isnan(x[k])) x[k] = -1e9f;
      lmax = fmaxf(lmax, x[k]);
    }
    float mx = block_reduce(lmax, true, sm);

    float lsum = 0.0f;
    #pragma unroll
    for (int k = 0; k < 4; ++k) if (k < nk) { x[k] = expf(x[k] - mx); lsum += x[k]; }
    float S = block_reduce(lsum, false, sm);

    float lss = 0.0f;
    #pragma unroll
    for (int k = 0; k < 4; ++k) if (k < nk) { float pk = x[k] / S; lss += pk * pk; }
    float ssq = block_reduce(lss, false, sm);
    float denom = fmaxf(sqrtf(ssq), 1e-12f);

    if (tid < 32) {
      int idx = gold[(b << 5) + tid];
      float xg = row[idx];
      if (isnan(xg)) xg = -1e9f;
      float pg = expf(xg - mx) / S;
      acc += w * (pg / denom);
    }
  }
  if (tid < 32) cost[(size_t)bq * 32 + tid] = -acc;
}

// ---------------------------------------------------------------------------
// Kernel 2: faithful replica of the reference's (buggy) JV loop.
// Proven from the reference source: minv stays INF (mv/wy are copies never
// written back) => delta == +INF always; way stays all-zero => augmentation
// collapses to p[j_final] = i. u in {0,+inf}, v in {0,-inf}. All comparisons
// are exact-fp32 vs +-inf, so fp32 reproduces the fp64 numpy behavior
// bit-for-bit, including first-index argmin tie-breaks. One wave per batch.
//
// Round-2 changes (251us -> ~10us predicted):
//  * cost block staged TRANSPOSED in LDS (ct[g][j], pad 513) -- the per-turn
//    column scan becomes a conflict-free LDS read instead of 128B-strided HBM.
//  * epilogue fully wave-parallel (rank sort in LDS) -- the old lane-0 serial
//    sort used dynamically-indexed private arrays => scratch memory => ~250us
//    of dependent scratch latency (rule #20). That was 93% of round-1 runtime.
// ---------------------------------------------------------------------------

__global__ __launch_bounds__(64) void hungarian_kernel(
    const float* __restrict__ cost, float* __restrict__ out)
{
  __shared__ float ct[32][513];  // ct[g][j] = cost[b][j][g], padded
  __shared__ float v[513];
  __shared__ float u[33];
  __shared__ int   p[513];
  __shared__ int   stamp[513];   // stamp[j] == i  <=>  used[j] this turn
  __shared__ int   rows_s[32];

  const int b    = blockIdx.x;
  const int lane = threadIdx.x;
  const float* cb = cost + (size_t)b * 512 * 32;
  const float INFV = __builtin_inff();

  // stage + transpose: 4096 float4 loads, coalesced; LDS writes <=2-way banked
  for (int base = lane; base < 4096; base += 64) {
    float4 val = reinterpret_cast<const float4*>(cb)[base];
    int e0 = base << 2;          // flat element index
    int j  = e0 >> 5;            // column (0..511)
    int g  = e0 & 31;            // gold row (0..28, step 4)
    ct[g + 0][j] = val.x;
    ct[g + 1][j] = val.y;
    ct[g + 2][j] = val.z;
    ct[g + 3][j] = val.w;
  }
  for (int j = lane; j < 513; j += 64) { v[j] = 0.0f; p[j] = 0; stamp[j] = -1; }
  if (lane < 33) u[lane] = 0.0f;
  __syncthreads();

  for (int i = 1; i <= 32; ++i) {
    if (lane == 0) p[0] = i;
    __syncthreads();
    int j0 = 0;
    for (int guard = 0; guard < 1024; ++guard) {
      int   i0  = p[j0];           // uniform LDS reads (pre-update values)
      float ui0 = u[i0];
      __syncthreads();
      if (lane == 0) { stamp[j0] = i; u[i0] = INFV; v[j0] = -INFV; }
      __syncthreads();

      // argmin over free j of key_j, first index wins. When ui0 == +inf the
      // cost term is irrelevant (x - inf = -inf for any finite x).
      float best = INFV; int bj = 0x7fffffff;
      const bool finite_u = (ui0 < INFV);
      #pragma unroll
      for (int k = 0; k < 8; ++k) {
        int j = 1 + lane + (k << 6);
        if (stamp[j] != i) {
          float ctv = finite_u ? ct[i0 - 1][j - 1] : 0.0f;
          float cur = ctv - ui0 - v[j];           // fp32 inf == fp64 inf here
          float key = (cur < INFV) ? cur : INFV;  // NaN -> INF (numpy mask)
          if (key < best || (key == best && j < bj)) { best = key; bj = j; }
        }
      }
      #pragma unroll
      for (int off = 32; off > 0; off >>= 1) {
        float ob = __shfl_xor(best, off);
        int   oj = __shfl_xor(bj, off);
        if (ob < best || (ob == best && oj < bj)) { best = ob; bj = oj; }
      }
      j0 = bj;
      if (j0 > 512) break;         // safety: cannot happen
      if (p[j0] == 0) break;       // unassigned column found
    }
    __syncthreads();
    if (lane == 0) p[j0] = i;      // augmentation with way == 0 collapses to this
    __syncthreads();
  }

  // ---- wave-parallel epilogue: rows extraction + rank sort (no scratch) ----
  for (int j = 1 + lane; j <= 512; j += 64) {
    int pi = p[j];
    if (pi > 0) rows_s[pi - 1] = j - 1;
  }
  __syncthreads();
  if (lane < 32) {
    int rv = rows_s[lane];
    int rank = 0;
    #pragma unroll
    for (int g = 0; g < 32; ++g) rank += (rows_s[g] < rv) ? 1 : 0;  // distinct
    out[131072 +       b * 32 + rank] = (float)rv;    // row_ind sorted asc
    out[131072 + 256 + b * 32 + rank] = (float)lane;  // matching col_ind
  }
}

// ---------------------------------------------------------------------------

extern "C" void kernel_launch(void* const* d_in, const int* in_sizes, int n_in,
                              void* d_out, int out_size, void* d_ws, size_t ws_size,
                              hipStream_t stream) {
  const float* rel = (const float*)d_in[0];
  const float* hs  = (const float*)d_in[1];
  const float* he  = (const float*)d_in[2];
  const float* ts  = (const float*)d_in[3];
  const float* te  = (const float*)d_in[4];
  const int* grel = (const int*)d_in[5];
  const int* ghs  = (const int*)d_in[6];
  const int* ghe  = (const int*)d_in[7];
  const int* gts  = (const int*)d_in[8];
  const int* gte  = (const int*)d_in[9];

  float* out  = (float*)d_out;
  float* cost = out;   // [8,512,32] -> first 131072 floats

  cost_kernel<<<8 * 512, 256, 0, stream>>>(rel, hs, he, ts, te,
                                           grel, ghs, ghe, gts, gte, cost);
  hungarian_kernel<<<8, 64, 0, stream>>>(cost, out);
}

// Round 3
// 71.863 us; speedup vs baseline: 3.7704x; 1.3355x over previous
//
#include <hip/hip_runtime.h>
#include <hip/hip_bf16.h>
#include <math.h>

// ---------------------------------------------------------------------------
// Kernel 1: cost matrix. UNCHANGED from round 2 (validated numerics).
// ---------------------------------------------------------------------------

__device__ __forceinline__ float block_reduce(float val, bool do_max, float* sm) {
  #pragma unroll
  for (int o = 32; o > 0; o >>= 1) {
    float other = __shfl_xor(val, o);
    val = do_max ? fmaxf(val, other) : (val + other);
  }
  __syncthreads();                       // protect sm from previous call's readers
  if ((threadIdx.x & 63) == 0) sm[threadIdx.x >> 6] = val;
  __syncthreads();
  float r = do_max ? fmaxf(fmaxf(sm[0], sm[1]), fmaxf(sm[2], sm[3]))
                   : ((sm[0] + sm[1]) + (sm[2] + sm[3]));
  return r;
}

__global__ __launch_bounds__(256) void cost_kernel(
    const float* __restrict__ rel,
    const float* __restrict__ hs, const float* __restrict__ he,
    const float* __restrict__ ts, const float* __restrict__ te,
    const int* __restrict__ grel,
    const int* __restrict__ ghs, const int* __restrict__ ghe,
    const int* __restrict__ gts, const int* __restrict__ gte,
    float* __restrict__ cost)
{
  __shared__ float sm[4];
  const int bq  = blockIdx.x;        // b*512 + q
  const int b   = bq >> 9;
  const int tid = threadIdx.x;
  float acc = 0.0f;                  // meaningful for tid < 32

  #pragma unroll
  for (int t = 0; t < 5; ++t) {
    const float* row; const int* gold; int nk; float w;
    switch (t) {
      case 0:  row = rel + (size_t)bq * 512;  gold = grel; nk = 2; w = 1.0f; break;
      case 1:  row = hs  + (size_t)bq * 1024; gold = ghs;  nk = 4; w = 0.5f; break;
      case 2:  row = he  + (size_t)bq * 1024; gold = ghe;  nk = 4; w = 0.5f; break;
      case 3:  row = ts  + (size_t)bq * 1024; gold = gts;  nk = 4; w = 0.5f; break;
      default: row = te  + (size_t)bq * 1024; gold = gte;  nk = 4; w = 0.5f; break;
    }
    float x[4];
    if (nk == 4) {
      float4 v4 = *reinterpret_cast<const float4*>(row + tid * 4);
      x[0] = v4.x; x[1] = v4.y; x[2] = v4.z; x[3] = v4.w;
    } else {
      float2 v2 = *reinterpret_cast<const float2*>(row + tid * 2);
      x[0] = v2.x; x[1] = v2.y; x[2] = 0.0f; x[3] = 0.0f;
    }
    float lmax = -INFINITY;
    #pragma unroll
    for (int k = 0; k < 4; ++k) if (k < nk) {
      if (isnan(x[k])) x[k] = -1e9f;
      lmax = fmaxf(lmax, x[k]);
    }
    float mx = block_reduce(lmax, true, sm);

    float lsum = 0.0f;
    #pragma unroll
    for (int k = 0; k < 4; ++k) if (k < nk) { x[k] = expf(x[k] - mx); lsum += x[k]; }
    float S = block_reduce(lsum, false, sm);

    float lss = 0.0f;
    #pragma unroll
    for (int k = 0; k < 4; ++k) if (k < nk) { float pk = x[k] / S; lss += pk * pk; }
    float ssq = block_reduce(lss, false, sm);
    float denom = fmaxf(sqrtf(ssq), 1e-12f);

    if (tid < 32) {
      int idx = gold[(b << 5) + tid];
      float xg = row[idx];
      if (isnan(xg)) xg = -1e9f;
      float pg = expf(xg - mx) / S;
      acc += w * (pg / denom);
    }
  }
  if (tid < 32) cost[(size_t)bq * 32 + tid] = -acc;
}

// ---------------------------------------------------------------------------
// Kernel 2: collapsed form of the reference's (buggy) JV loop.
//
// Proven from the reference source: minv stays INF (mv/wy are copies never
// written back) => delta == +INF every iteration. Therefore each turn r
// (row r of C^T) reduces EXACTLY to:
//   j1 = argmin over alive columns (v[j]==0) of C[r][j]   (first-index ties;
//        dead columns give C-(-inf)=+inf -> excluded; NaN -> excluded)
//   if free(j1):  assign j1 to r  (j1 STAYS alive: the turn's final column
//                 never receives v=-inf)
//   else:         kill j1; the u=inf iterations make all alive columns tie
//                 at -inf, so the loop walks alive columns in ascending index
//                 killing assigned ones until the first alive free column jF;
//                 assign jF (stays alive).
//                 == { jF = min{j: alive&free}; kill alive j<jF and j1 }
// free => alive always holds, so jF exists. fp32 reproduces the fp64 numpy
// comparisons bit-for-bit (exact f32 values vs +-inf), incl. tie-breaks.
//
// State is 2 register bitmasks per lane (8 columns/lane, j = lane + 64k).
// No LDS writes and NO barriers inside the turn loop; next row's ct reads
// are prefetched so LDS latency hides under the butterfly reduce.
// ---------------------------------------------------------------------------

__global__ __launch_bounds__(64) void hungarian_kernel(
    const float* __restrict__ cost, float* __restrict__ out)
{
  __shared__ float ct[32][513];  // ct[g][j] = cost[b][j][g]; bank = (g+j)%32
  __shared__ int   rows_s[32];

  const int b    = blockIdx.x;
  const int lane = threadIdx.x;
  const float* cb = cost + (size_t)b * 512 * 32;
  const float INFV = __builtin_inff();

  // stage + transpose: coalesced float4 loads, <=2-way banked LDS writes
  for (int base = lane; base < 4096; base += 64) {
    float4 val = reinterpret_cast<const float4*>(cb)[base];
    int e0 = base << 2;          // flat element index
    int j  = e0 >> 5;            // column (0..511)
    int g  = e0 & 31;            // gold row (multiple of 4)
    ct[g + 0][j] = val.x;
    ct[g + 1][j] = val.y;
    ct[g + 2][j] = val.z;
    ct[g + 3][j] = val.w;
  }
  __syncthreads();

  unsigned int alive = 0xFFu;    // bit k: column j = lane + 64k has v[j]==0
  unsigned int freem = 0xFFu;    // bit k: column j = lane + 64k unassigned

  // prefetch row 0 (conflict-free: bank = (r + lane) % 32, 2 lanes/bank)
  float x[8];
  #pragma unroll
  for (int k = 0; k < 8; ++k) x[k] = ct[0][lane + (k << 6)];

  for (int r = 0; r < 32; ++r) {
    float cur[8];
    #pragma unroll
    for (int k = 0; k < 8; ++k) cur[k] = x[k];
    if (r < 31) {                // prefetch next row; hides under the reduce
      #pragma unroll
      for (int k = 0; k < 8; ++k) x[k] = ct[r + 1][lane + (k << 6)];
    }

    // local masked argmin over this lane's 8 columns (k asc == j asc here)
    float best  = INFV;
    int   bmeta = 0x7FFFFFFF;    // (j << 1) | free  — j dominates ordering
    #pragma unroll
    for (int k = 0; k < 8; ++k) {
      bool  a   = (alive >> k) & 1u;
      float v   = cur[k];
      float key = (a && v < INFV) ? v : INFV;   // dead/NaN -> INF (excluded)
      int   meta = ((lane + (k << 6)) << 1) | (int)((freem >> k) & 1u);
      if (key < best || (key == best && meta < bmeta)) { best = key; bmeta = meta; }
    }
    // 6-step butterfly argmin, first-j tie-break, free-flag rides in meta
    #pragma unroll
    for (int off = 32; off > 0; off >>= 1) {
      float ob = __shfl_xor(best, off);
      int   om = __shfl_xor(bmeta, off);
      if (ob < best || (ob == best && om < bmeta)) { best = ob; bmeta = om; }
    }
    int  j1 = bmeta >> 1;
    int  jwin;
    if (bmeta & 1) {             // j1 free: assign it, stays alive
      jwin = j1;
    } else {                     // j1 assigned: kill it, walk to first alive free
      if (lane == (j1 & 63)) alive &= ~(1u << (j1 >> 6));
      unsigned int cm = alive & freem;
      int cand = cm ? (lane + (__builtin_ctz(cm) << 6)) : 0x7FFFFFFF;
      #pragma unroll
      for (int off = 32; off > 0; off >>= 1) {
        int oc = __shfl_xor(cand, off);
        cand = min(cand, oc);
      }
      int jF = cand;
      // kill all alive columns with j < jF (all are assigned by minimality)
      int d = jF - lane;         // j = lane + 64k < jF  <=>  k < d/64
      int K = d > 0 ? ((d + 63) >> 6) : 0;
      if (K > 8) K = 8;
      alive &= ~((1u << K) - 1u);
      jwin = jF;                 // jF stays alive
    }
    if (lane == (jwin & 63)) freem &= ~(1u << (jwin >> 6));
    if (lane == 0) rows_s[r] = jwin;   // rows[g=r] = assigned query column
  }
  __syncthreads();

  // wave-parallel epilogue: rank sort (values distinct), no scratch
  if (lane < 32) {
    int rv = rows_s[lane];
    int rank = 0;
    #pragma unroll
    for (int g = 0; g < 32; ++g) rank += (rows_s[g] < rv) ? 1 : 0;
    out[131072 +       b * 32 + rank] = (float)rv;    // row_ind sorted asc
    out[131072 + 256 + b * 32 + rank] = (float)lane;  // matching col_ind
  }
}

// ---------------------------------------------------------------------------

extern "C" void kernel_launch(void* const* d_in, const int* in_sizes, int n_in,
                              void* d_out, int out_size, void* d_ws, size_t ws_size,
                              hipStream_t stream) {
  const float* rel = (const float*)d_in[0];
  const float* hs  = (const float*)d_in[1];
  const float* he  = (const float*)d_in[2];
  const float* ts  = (const float*)d_in[3];
  const float* te  = (const float*)d_in[4];
  const int* grel = (const int*)d_in[5];
  const int* ghs  = (const int*)d_in[6];
  const int* ghe  = (const int*)d_in[7];
  const int* gts  = (const int*)d_in[8];
  const int* gte  = (const int*)d_in[9];

  float* out  = (float*)d_out;
  float* cost = out;   // [8,512,32] -> first 131072 floats

  cost_kernel<<<8 * 512, 256, 0, stream>>>(rel, hs, he, ts, te,
                                           grel, ghs, ghe, gts, gte, cost);
  hungarian_kernel<<<8, 64, 0, stream>>>(cost, out);
}

// Round 4
// 64.886 us; speedup vs baseline: 4.1758x; 1.1075x over previous
//
#include <hip/hip_runtime.h>
#include <hip/hip_bf16.h>
#include <math.h>

// ---------------------------------------------------------------------------
// Kernel 1: cost matrix. UNCHANGED from rounds 2-3 (validated numerics —
// do not touch: argmin tie stability depends on exact bit patterns).
// ---------------------------------------------------------------------------

__device__ __forceinline__ float block_reduce(float val, bool do_max, float* sm) {
  #pragma unroll
  for (int o = 32; o > 0; o >>= 1) {
    float other = __shfl_xor(val, o);
    val = do_max ? fmaxf(val, other) : (val + other);
  }
  __syncthreads();                       // protect sm from previous call's readers
  if ((threadIdx.x & 63) == 0) sm[threadIdx.x >> 6] = val;
  __syncthreads();
  float r = do_max ? fmaxf(fmaxf(sm[0], sm[1]), fmaxf(sm[2], sm[3]))
                   : ((sm[0] + sm[1]) + (sm[2] + sm[3]));
  return r;
}

__global__ __launch_bounds__(256) void cost_kernel(
    const float* __restrict__ rel,
    const float* __restrict__ hs, const float* __restrict__ he,
    const float* __restrict__ ts, const float* __restrict__ te,
    const int* __restrict__ grel,
    const int* __restrict__ ghs, const int* __restrict__ ghe,
    const int* __restrict__ gts, const int* __restrict__ gte,
    float* __restrict__ cost)
{
  __shared__ float sm[4];
  const int bq  = blockIdx.x;        // b*512 + q
  const int b   = bq >> 9;
  const int tid = threadIdx.x;
  float acc = 0.0f;                  // meaningful for tid < 32

  #pragma unroll
  for (int t = 0; t < 5; ++t) {
    const float* row; const int* gold; int nk; float w;
    switch (t) {
      case 0:  row = rel + (size_t)bq * 512;  gold = grel; nk = 2; w = 1.0f; break;
      case 1:  row = hs  + (size_t)bq * 1024; gold = ghs;  nk = 4; w = 0.5f; break;
      case 2:  row = he  + (size_t)bq * 1024; gold = ghe;  nk = 4; w = 0.5f; break;
      case 3:  row = ts  + (size_t)bq * 1024; gold = gts;  nk = 4; w = 0.5f; break;
      default: row = te  + (size_t)bq * 1024; gold = gte;  nk = 4; w = 0.5f; break;
    }
    float x[4];
    if (nk == 4) {
      float4 v4 = *reinterpret_cast<const float4*>(row + tid * 4);
      x[0] = v4.x; x[1] = v4.y; x[2] = v4.z; x[3] = v4.w;
    } else {
      float2 v2 = *reinterpret_cast<const float2*>(row + tid * 2);
      x[0] = v2.x; x[1] = v2.y; x[2] = 0.0f; x[3] = 0.0f;
    }
    float lmax = -INFINITY;
    #pragma unroll
    for (int k = 0; k < 4; ++k) if (k < nk) {
      if (isnan(x[k])) x[k] = -1e9f;
      lmax = fmaxf(lmax, x[k]);
    }
    float mx = block_reduce(lmax, true, sm);

    float lsum = 0.0f;
    #pragma unroll
    for (int k = 0; k < 4; ++k) if (k < nk) { x[k] = expf(x[k] - mx); lsum += x[k]; }
    float S = block_reduce(lsum, false, sm);

    float lss = 0.0f;
    #pragma unroll
    for (int k = 0; k < 4; ++k) if (k < nk) { float pk = x[k] / S; lss += pk * pk; }
    float ssq = block_reduce(lss, false, sm);
    float denom = fmaxf(sqrtf(ssq), 1e-12f);

    if (tid < 32) {
      int idx = gold[(b << 5) + tid];
      float xg = row[idx];
      if (isnan(xg)) xg = -1e9f;
      float pg = expf(xg - mx) / S;
      acc += w * (pg / denom);
    }
  }
  if (tid < 32) cost[(size_t)bq * 32 + tid] = -acc;
}

// ---------------------------------------------------------------------------
// Kernel 2: collapsed reference-JV replica (see round-3 derivation, twice
// validated). Round-4 changes — attack the cross-lane dependent latency:
//  * butterfly steps xor1/xor2/xor7/xor15 via DPP (quad_perm 0xB1/0x4E,
//    row_half_mirror 0x141, row_mirror 0x140) — VALU-pipe (~10cy) instead of
//    ds_swizzle (~120cy). Coverage {1,2,7,15,16,32} spans all 64 lanes.
//  * the assigned-branch's SECOND butterfly (first alive&free column) is
//    fused into the main reduction as a third payload fj (v_min_i32/step) —
//    valid pre-branch because j1 is assigned => not in the alive&free set.
//  * local 8-way argmin: linear chain -> pairwise tree (depth 3).
// ---------------------------------------------------------------------------

template <int CTRL>
__device__ __forceinline__ int dpp_mov(int x) {
  return __builtin_amdgcn_update_dpp(0, x, CTRL, 0xF, 0xF, true);
}

__device__ __forceinline__ void amin(float& k0, int& m0, float k1, int m1) {
  bool take = (k1 < k0) || (k1 == k0 && m1 < m0);
  k0 = take ? k1 : k0;
  m0 = take ? m1 : m0;
}

__global__ __launch_bounds__(64) void hungarian_kernel(
    const float* __restrict__ cost, float* __restrict__ out)
{
  __shared__ float ct[32][513];  // ct[g][j] = cost[b][j][g]; bank = (g+j)%32
  __shared__ int   rows_s[32];

  const int b    = blockIdx.x;
  const int lane = threadIdx.x;
  const float* cb = cost + (size_t)b * 512 * 32;
  const float INFV = __builtin_inff();

  // stage + transpose: coalesced float4 loads, <=2-way banked LDS writes
  #pragma unroll 8
  for (int base = lane; base < 4096; base += 64) {
    float4 val = reinterpret_cast<const float4*>(cb)[base];
    int e0 = base << 2;          // flat element index
    int j  = e0 >> 5;            // column (0..511)
    int g  = e0 & 31;            // gold row (multiple of 4)
    ct[g + 0][j] = val.x;
    ct[g + 1][j] = val.y;
    ct[g + 2][j] = val.z;
    ct[g + 3][j] = val.w;
  }
  __syncthreads();

  unsigned int alive = 0xFFu;    // bit k: column j = lane + 64k has v[j]==0
  unsigned int freem = 0xFFu;    // bit k: column j = lane + 64k unassigned

  // prefetch row 0 (conflict-free: bank = (r + lane) % 32)
  float x[8];
  #pragma unroll
  for (int k = 0; k < 8; ++k) x[k] = ct[0][lane + (k << 6)];

  for (int r = 0; r < 32; ++r) {
    float cur[8];
    #pragma unroll
    for (int k = 0; k < 8; ++k) cur[k] = x[k];
    if (r < 31) {                // prefetch next row; hides under the reduce
      #pragma unroll
      for (int k = 0; k < 8; ++k) x[k] = ct[r + 1][lane + (k << 6)];
    }

    // ---- local masked argmin over this lane's 8 columns (tree, depth 3) ----
    float ky[8]; int mt[8];
    #pragma unroll
    for (int k = 0; k < 8; ++k) {
      bool a = (alive >> k) & 1u;
      float v = cur[k];
      ky[k] = (a && v < INFV) ? v : INFV;    // dead/NaN -> INF (excluded)
      mt[k] = ((lane + (k << 6)) << 1) | (int)((freem >> k) & 1u);
    }
    amin(ky[0], mt[0], ky[1], mt[1]); amin(ky[2], mt[2], ky[3], mt[3]);
    amin(ky[4], mt[4], ky[5], mt[5]); amin(ky[6], mt[6], ky[7], mt[7]);
    amin(ky[0], mt[0], ky[2], mt[2]); amin(ky[4], mt[4], ky[6], mt[6]);
    amin(ky[0], mt[0], ky[4], mt[4]);
    float bkey = ky[0]; int bmeta = mt[0];

    // fj = this lane's min alive&free column (k asc == j asc for fixed lane)
    unsigned int cm = alive & freem;
    int bfj = 0x7FFFFFFF;
    if (cm) bfj = lane + (__builtin_ctz(cm) << 6);

    // ---- fused 6-step butterfly: argmin(key,meta) + min(fj) ----
    #define BF_STEP(GETK, GETM, GETF)                                        \
      { float okf = (GETK); int om = (GETM); int of = (GETF);                \
        bool take = (okf < bkey) || (okf == bkey && om < bmeta);             \
        bkey = take ? okf : bkey; bmeta = take ? om : bmeta;                 \
        bfj = min(bfj, of); }

    BF_STEP(__int_as_float(dpp_mov<0xB1>(__float_as_int(bkey))),   // xor1
            dpp_mov<0xB1>(bmeta),  dpp_mov<0xB1>(bfj))
    BF_STEP(__int_as_float(dpp_mov<0x4E>(__float_as_int(bkey))),   // xor2
            dpp_mov<0x4E>(bmeta),  dpp_mov<0x4E>(bfj))
    BF_STEP(__int_as_float(dpp_mov<0x141>(__float_as_int(bkey))),  // xor7
            dpp_mov<0x141>(bmeta), dpp_mov<0x141>(bfj))
    BF_STEP(__int_as_float(dpp_mov<0x140>(__float_as_int(bkey))),  // xor15
            dpp_mov<0x140>(bmeta), dpp_mov<0x140>(bfj))
    BF_STEP(__shfl_xor(bkey, 16), __shfl_xor(bmeta, 16), __shfl_xor(bfj, 16))
    BF_STEP(__shfl_xor(bkey, 32), __shfl_xor(bmeta, 32), __shfl_xor(bfj, 32))
    #undef BF_STEP

    int j1 = bmeta >> 1;
    int jwin;
    if (bmeta & 1) {             // j1 free: assign it, stays alive
      jwin = j1;
    } else {                     // j1 assigned: kill it; jF = first alive free
      if (lane == (j1 & 63)) alive &= ~(1u << (j1 >> 6));
      int jF = bfj;
      // kill all alive columns with j < jF (all assigned, by minimality)
      int d = jF - lane;         // j = lane + 64k < jF  <=>  k < ceil(d/64)
      int K = d > 0 ? ((d + 63) >> 6) : 0;
      if (K > 8) K = 8;
      alive &= ~((1u << K) - 1u);
      jwin = jF;                 // jF stays alive
    }
    if (lane == (jwin & 63)) freem &= ~(1u << (jwin >> 6));
    if (lane == 0) rows_s[r] = jwin;   // rows[g=r] = assigned query column
  }
  __syncthreads();

  // wave-parallel epilogue: rank sort (values distinct), no scratch
  if (lane < 32) {
    int rv = rows_s[lane];
    int rank = 0;
    #pragma unroll
    for (int g = 0; g < 32; ++g) rank += (rows_s[g] < rv) ? 1 : 0;
    out[131072 +       b * 32 + rank] = (float)rv;    // row_ind sorted asc
    out[131072 + 256 + b * 32 + rank] = (float)lane;  // matching col_ind
  }
}

// ---------------------------------------------------------------------------

extern "C" void kernel_launch(void* const* d_in, const int* in_sizes, int n_in,
                              void* d_out, int out_size, void* d_ws, size_t ws_size,
                              hipStream_t stream) {
  const float* rel = (const float*)d_in[0];
  const float* hs  = (const float*)d_in[1];
  const float* he  = (const float*)d_in[2];
  const float* ts  = (const float*)d_in[3];
  const float* te  = (const float*)d_in[4];
  const int* grel = (const int*)d_in[5];
  const int* ghs  = (const int*)d_in[6];
  const int* ghe  = (const int*)d_in[7];
  const int* gts  = (const int*)d_in[8];
  const int* gte  = (const int*)d_in[9];

  float* out  = (float*)d_out;
  float* cost = out;   // [8,512,32] -> first 131072 floats

  cost_kernel<<<8 * 512, 256, 0, stream>>>(rel, hs, he, ts, te,
                                           grel, ghs, ghe, gts, gte, cost);
  hungarian_kernel<<<8, 64, 0, stream>>>(cost, out);
}

// Round 5
// 58.240 us; speedup vs baseline: 4.6523x; 1.1141x over previous
//
#include <hip/hip_runtime.h>
#include <hip/hip_bf16.h>
#include <math.h>

// ---------------------------------------------------------------------------
// DPP helpers. Controls: 0xB1 quad_perm(1,0,3,2)=xor1 (exact), 0x4E
// quad_perm(2,3,0,1)=xor2 (exact), 0x141 row_half_mirror=xor7 (exact),
// 0x140 row_mirror=xor15 (exact), 0x142 row_bcast15, 0x143 row_bcast31.
// ---------------------------------------------------------------------------
template <int CTRL>
__device__ __forceinline__ int dpp_i(int x) {
  return __builtin_amdgcn_update_dpp(0, x, CTRL, 0xF, 0xF, true);
}
template <int CTRL>
__device__ __forceinline__ float dpp_f(float x) {
  return __int_as_float(__builtin_amdgcn_update_dpp(0, __float_as_int(x), CTRL, 0xF, 0xF, true));
}

// ---------------------------------------------------------------------------
// Kernel 1: cost matrix — one WAVE per (b,q) row, 4 rows per 256-block.
// Numerically BIT-IDENTICAL to the validated round-2..4 version: real lane l
// emulates virtual lanes {l, 64+l, 128+l, 192+l} of the old 256-thread block.
// The 4 per-virtual-wave butterflies (xor 32,16,8,4,2,1 — same order, same
// pairing) run as 4 parallel register chains; the final (sm0+sm1)+(sm2+sm3)
// combine is replicated per-lane. Sum trees identical => same bits.
// Max-reduce is order-free (fmax exact), so it may use any shape: full-DPP
// chain + row_bcast finale + readlane broadcast. No barriers, no LDS.
// ---------------------------------------------------------------------------

__global__ __launch_bounds__(256, 4) void cost_kernel(
    const float* __restrict__ rel,
    const float* __restrict__ hs, const float* __restrict__ he,
    const float* __restrict__ ts, const float* __restrict__ te,
    const int* __restrict__ grel,
    const int* __restrict__ ghs, const int* __restrict__ ghe,
    const int* __restrict__ gts, const int* __restrict__ gte,
    float* __restrict__ cost)
{
  const int wid  = threadIdx.x >> 6;             // wave in block: 0..3
  const int lane = threadIdx.x & 63;
  const int bq   = (blockIdx.x << 2) | wid;      // row id: b*512 + q
  const int b    = bq >> 9;
  float acc = 0.0f;                              // meaningful for lane < 32

  #pragma unroll
  for (int t = 0; t < 5; ++t) {
    const float* row; const int* gold; int nk; float w;
    switch (t) {
      case 0:  row = rel + (size_t)bq * 512;  gold = grel; nk = 2; w = 1.0f; break;
      case 1:  row = hs  + (size_t)bq * 1024; gold = ghs;  nk = 4; w = 0.5f; break;
      case 2:  row = he  + (size_t)bq * 1024; gold = ghe;  nk = 4; w = 0.5f; break;
      case 3:  row = ts  + (size_t)bq * 1024; gold = gts;  nk = 4; w = 0.5f; break;
      default: row = te  + (size_t)bq * 1024; gold = gte;  nk = 4; w = 0.5f; break;
    }
    // virtual lane t = k*64 + lane holds elements [nk*t, nk*t+nk)
    float x[4][4];
    if (nk == 4) {
      #pragma unroll
      for (int k = 0; k < 4; ++k) {
        float4 v4 = *reinterpret_cast<const float4*>(row + (k << 8) + lane * 4);
        x[k][0] = v4.x; x[k][1] = v4.y; x[k][2] = v4.z; x[k][3] = v4.w;
      }
    } else {
      #pragma unroll
      for (int k = 0; k < 4; ++k) {
        float2 v2 = *reinterpret_cast<const float2*>(row + (k << 7) + lane * 2);
        x[k][0] = v2.x; x[k][1] = v2.y; x[k][2] = 0.0f; x[k][3] = 0.0f;
      }
    }

    // ---- max (order-free: any tree gives identical fmax result) ----
    float m = -INFINITY;
    #pragma unroll
    for (int k = 0; k < 4; ++k) {
      #pragma unroll
      for (int e = 0; e < 4; ++e) if (e < nk) {
        if (isnan(x[k][e])) x[k][e] = -1e9f;
        m = fmaxf(m, x[k][e]);
      }
    }
    m = fmaxf(m, dpp_f<0xB1>(m));    // xor1
    m = fmaxf(m, dpp_f<0x4E>(m));    // xor2
    m = fmaxf(m, dpp_f<0x141>(m));   // xor7
    m = fmaxf(m, dpp_f<0x140>(m));   // xor15  -> 16-group max everywhere
    m = fmaxf(m, dpp_f<0x142>(m));   // row_bcast15
    m = fmaxf(m, dpp_f<0x143>(m));   // row_bcast31 -> lane63 = global max
    float mx = __int_as_float(__builtin_amdgcn_readlane(__float_as_int(m), 63));

    // ---- exp + sum (EXACT tree replication of old block_reduce) ----
    float ps[4];
    #pragma unroll
    for (int k = 0; k < 4; ++k) {
      float ls = 0.0f;
      #pragma unroll
      for (int e = 0; e < 4; ++e) if (e < nk) { x[k][e] = expf(x[k][e] - mx); ls += x[k][e]; }
      ps[k] = ls;
    }
    #pragma unroll
    for (int k = 0; k < 4; ++k) {
      ps[k] += __shfl_xor(ps[k], 32);
      ps[k] += __shfl_xor(ps[k], 16);
      ps[k] += __shfl_xor(ps[k], 8);
      ps[k] += __shfl_xor(ps[k], 4);
      ps[k] += dpp_f<0x4E>(ps[k]);   // xor2 — exact same pairing as shfl
      ps[k] += dpp_f<0xB1>(ps[k]);   // xor1 — exact same pairing as shfl
    }
    float S = (ps[0] + ps[1]) + (ps[2] + ps[3]);

    // ---- sum of p^2 (same exact tree) ----
    float pq[4];
    #pragma unroll
    for (int k = 0; k < 4; ++k) {
      float ls = 0.0f;
      #pragma unroll
      for (int e = 0; e < 4; ++e) if (e < nk) { float p = x[k][e] / S; ls += p * p; }
      pq[k] = ls;
    }
    #pragma unroll
    for (int k = 0; k < 4; ++k) {
      pq[k] += __shfl_xor(pq[k], 32);
      pq[k] += __shfl_xor(pq[k], 16);
      pq[k] += __shfl_xor(pq[k], 8);
      pq[k] += __shfl_xor(pq[k], 4);
      pq[k] += dpp_f<0x4E>(pq[k]);
      pq[k] += dpp_f<0xB1>(pq[k]);
    }
    float ssq = (pq[0] + pq[1]) + (pq[2] + pq[3]);
    float denom = fmaxf(sqrtf(ssq), 1e-12f);

    if (lane < 32) {
      int idx = gold[(b << 5) + lane];
      float xg = row[idx];
      if (isnan(xg)) xg = -1e9f;
      float pg = expf(xg - mx) / S;
      acc += w * (pg / denom);
    }
  }
  if (lane < 32) cost[(size_t)bq * 32 + lane] = -acc;
}

// ---------------------------------------------------------------------------
// Kernel 2: collapsed reference-JV replica (derivation validated rounds 3-4).
// Round-5: the turn-loop reduction is now 100% VALU-pipe — DPP steps
// xor1/xor2/xor7/xor15 (exact) + row_bcast15 + row_bcast31 + readlane(63).
// No ds_swizzle/ds_bpermute in the dependent chain. j1/jF live in SGPRs
// (free broadcast, uniform branch). Bound-ctrl zero-fill only pollutes lanes
// whose DPP source is invalid (0-15 / 0-31 on bcast steps); lane 63's
// reduction path (47 -> 31 after bcast15) reads only valid lanes.
// ---------------------------------------------------------------------------

__device__ __forceinline__ void amin(float& k0, int& m0, float k1, int m1) {
  bool take = (k1 < k0) || (k1 == k0 && m1 < m0);
  k0 = take ? k1 : k0;
  m0 = take ? m1 : m0;
}

__global__ __launch_bounds__(64) void hungarian_kernel(
    const float* __restrict__ cost, float* __restrict__ out)
{
  __shared__ float ct[32][513];  // ct[g][j] = cost[b][j][g]; bank = (g+j)%32
  __shared__ int   rows_s[32];

  const int b    = blockIdx.x;
  const int lane = threadIdx.x;
  const float* cb = cost + (size_t)b * 512 * 32;
  const float INFV = __builtin_inff();

  // stage + transpose: coalesced float4 loads, <=2-way banked LDS writes
  #pragma unroll 8
  for (int base = lane; base < 4096; base += 64) {
    float4 val = reinterpret_cast<const float4*>(cb)[base];
    int e0 = base << 2;          // flat element index
    int j  = e0 >> 5;            // column (0..511)
    int g  = e0 & 31;            // gold row (multiple of 4)
    ct[g + 0][j] = val.x;
    ct[g + 1][j] = val.y;
    ct[g + 2][j] = val.z;
    ct[g + 3][j] = val.w;
  }
  __syncthreads();

  unsigned int alive = 0xFFu;    // bit k: column j = lane + 64k has v[j]==0
  unsigned int freem = 0xFFu;    // bit k: column j = lane + 64k unassigned
  int mtb[8];
  #pragma unroll
  for (int k = 0; k < 8; ++k) mtb[k] = (lane + (k << 6)) << 1;

  // prefetch row 0 (conflict-free: bank = (r + lane) % 32)
  float x[8];
  #pragma unroll
  for (int k = 0; k < 8; ++k) x[k] = ct[0][lane + (k << 6)];

  for (int r = 0; r < 32; ++r) {
    float cur[8];
    #pragma unroll
    for (int k = 0; k < 8; ++k) cur[k] = x[k];
    if (r < 31) {                // prefetch next row; hides under the reduce
      #pragma unroll
      for (int k = 0; k < 8; ++k) x[k] = ct[r + 1][lane + (k << 6)];
    }

    // ---- local masked argmin over this lane's 8 columns (tree, depth 3) ----
    float ky[8]; int mt[8];
    #pragma unroll
    for (int k = 0; k < 8; ++k) {
      bool a = (alive >> k) & 1u;
      float v = cur[k];
      ky[k] = (a && v < INFV) ? v : INFV;    // dead/NaN -> INF (excluded)
      mt[k] = mtb[k] | (int)((freem >> k) & 1u);
    }
    amin(ky[0], mt[0], ky[1], mt[1]); amin(ky[2], mt[2], ky[3], mt[3]);
    amin(ky[4], mt[4], ky[5], mt[5]); amin(ky[6], mt[6], ky[7], mt[7]);
    amin(ky[0], mt[0], ky[2], mt[2]); amin(ky[4], mt[4], ky[6], mt[6]);
    amin(ky[0], mt[0], ky[4], mt[4]);
    float bkey = ky[0]; int bmeta = mt[0];

    // fj = this lane's min alive&free column (k asc == j asc for fixed lane)
    unsigned int cm = alive & freem;
    int bfj = cm ? (lane + (__builtin_ctz(cm) << 6)) : 0x7FFFFFFF;

    // ---- all-VALU 6-step reduce: argmin(key,meta) + min(fj) ----
    #define BF_STEP(OPK, OPM, OPF)                                           \
      { float ok = (OPK); int om = (OPM); int of = (OPF);                    \
        bool take = (ok < bkey) || (ok == bkey && om < bmeta);               \
        bkey = take ? ok : bkey; bmeta = take ? om : bmeta;                  \
        bfj = min(bfj, of); }

    BF_STEP(dpp_f<0xB1>(bkey),  dpp_i<0xB1>(bmeta),  dpp_i<0xB1>(bfj))   // xor1
    BF_STEP(dpp_f<0x4E>(bkey),  dpp_i<0x4E>(bmeta),  dpp_i<0x4E>(bfj))   // xor2
    BF_STEP(dpp_f<0x141>(bkey), dpp_i<0x141>(bmeta), dpp_i<0x141>(bfj))  // xor7
    BF_STEP(dpp_f<0x140>(bkey), dpp_i<0x140>(bmeta), dpp_i<0x140>(bfj))  // xor15
    BF_STEP(dpp_f<0x142>(bkey), dpp_i<0x142>(bmeta), dpp_i<0x142>(bfj))  // bcast15
    BF_STEP(dpp_f<0x143>(bkey), dpp_i<0x143>(bmeta), dpp_i<0x143>(bfj))  // bcast31
    #undef BF_STEP

    const int smeta = __builtin_amdgcn_readlane(bmeta, 63);  // uniform
    const int sfj   = __builtin_amdgcn_readlane(bfj, 63);    // uniform
    const int j1    = smeta >> 1;

    int jwin;
    if (smeta & 1) {             // j1 free: assign it, stays alive
      jwin = j1;
    } else {                     // j1 assigned: kill it; jF = first alive free
      if (lane == (j1 & 63)) alive &= ~(1u << (j1 >> 6));
      // kill all alive columns with j < jF (all assigned, by minimality)
      int d = sfj - lane;        // j = lane + 64k < jF  <=>  k < ceil(d/64)
      int K = d > 0 ? ((d + 63) >> 6) : 0;
      if (K > 8) K = 8;
      alive &= ~((1u << K) - 1u);
      jwin = sfj;                // jF stays alive
    }
    if (lane == (jwin & 63)) freem &= ~(1u << (jwin >> 6));
    if (lane == 0) rows_s[r] = jwin;   // rows[g=r] = assigned query column
  }
  __syncthreads();

  // wave-parallel epilogue: rank sort (values distinct), no scratch
  if (lane < 32) {
    int rv = rows_s[lane];
    int rank = 0;
    #pragma unroll
    for (int g = 0; g < 32; ++g) rank += (rows_s[g] < rv) ? 1 : 0;
    out[131072 +       b * 32 + rank] = (float)rv;    // row_ind sorted asc
    out[131072 + 256 + b * 32 + rank] = (float)lane;  // matching col_ind
  }
}

// ---------------------------------------------------------------------------

extern "C" void kernel_launch(void* const* d_in, const int* in_sizes, int n_in,
                              void* d_out, int out_size, void* d_ws, size_t ws_size,
                              hipStream_t stream) {
  const float* rel = (const float*)d_in[0];
  const float* hs  = (const float*)d_in[1];
  const float* he  = (const float*)d_in[2];
  const float* ts  = (const float*)d_in[3];
  const float* te  = (const float*)d_in[4];
  const int* grel = (const int*)d_in[5];
  const int* ghs  = (const int*)d_in[6];
  const int* ghe  = (const int*)d_in[7];
  const int* gts  = (const int*)d_in[8];
  const int* gte  = (const int*)d_in[9];

  float* out  = (float*)d_out;
  float* cost = out;   // [8,512,32] -> first 131072 floats

  cost_kernel<<<1024, 256, 0, stream>>>(rel, hs, he, ts, te,
                                        grel, ghs, ghe, gts, gte, cost);
  hungarian_kernel<<<8, 64, 0, stream>>>(cost, out);
}

// Round 6
// 55.113 us; speedup vs baseline: 4.9163x; 1.0567x over previous
//
#include <hip/hip_runtime.h>
#include <hip/hip_bf16.h>
#include <math.h>

// ---------------------------------------------------------------------------
// DPP helpers. Controls: 0xB1 quad_perm(1,0,3,2)=xor1 (exact), 0x4E
// quad_perm(2,3,0,1)=xor2 (exact), 0x141 row_half_mirror=xor7 (exact),
// 0x140 row_mirror=xor15 (exact), 0x142 row_bcast15, 0x143 row_bcast31.
// ---------------------------------------------------------------------------
template <int CTRL>
__device__ __forceinline__ int dpp_i(int x) {
  return __builtin_amdgcn_update_dpp(0, x, CTRL, 0xF, 0xF, true);
}
template <int CTRL>
__device__ __forceinline__ float dpp_f(float x) {
  return __int_as_float(__builtin_amdgcn_update_dpp(0, __float_as_int(x), CTRL, 0xF, 0xF, true));
}

// ---------------------------------------------------------------------------
// Per-tensor normalized-softmax gather:  c = e_g / sqrt(sum e^2), where
// e = exp(x - max). Algebraically identical to the reference's
// (e_g/S)/sqrt(sum (e/S)^2) — the softmax denominator S cancels exactly, so
// we skip the S-reduction and all per-element divisions (~1ulp relative
// perturbation; reference clamp max(.,1e-12) is never active since
// sqrt(sum e^2) >= 1). Reduction trees keep the validated round-5 shape.
// NK = elements per virtual lane (2 for D=512, 4 for D=1024).
// ---------------------------------------------------------------------------
template <int NK>
__device__ __forceinline__ float tensor_c(const float* __restrict__ row,
                                          int idx, int lane) {
  float x[4][4];
  float xg = row[idx];                         // gather hoisted before reduces
  if (NK == 4) {
    #pragma unroll
    for (int k = 0; k < 4; ++k) {
      float4 v4 = *reinterpret_cast<const float4*>(row + (k << 8) + lane * 4);
      x[k][0] = v4.x; x[k][1] = v4.y; x[k][2] = v4.z; x[k][3] = v4.w;
    }
  } else {
    #pragma unroll
    for (int k = 0; k < 4; ++k) {
      float2 v2 = *reinterpret_cast<const float2*>(row + (k << 7) + lane * 2);
      x[k][0] = v2.x; x[k][1] = v2.y; x[k][2] = 0.0f; x[k][3] = 0.0f;
    }
  }

  // ---- max (order-free; validated DPP chain) ----
  float m = -INFINITY;
  #pragma unroll
  for (int k = 0; k < 4; ++k) {
    #pragma unroll
    for (int e = 0; e < 4; ++e) if (e < NK) {
      if (isnan(x[k][e])) x[k][e] = -1e9f;
      m = fmaxf(m, x[k][e]);
    }
  }
  m = fmaxf(m, dpp_f<0xB1>(m));
  m = fmaxf(m, dpp_f<0x4E>(m));
  m = fmaxf(m, dpp_f<0x141>(m));
  m = fmaxf(m, dpp_f<0x140>(m));
  m = fmaxf(m, dpp_f<0x142>(m));
  m = fmaxf(m, dpp_f<0x143>(m));
  float mx = __int_as_float(__builtin_amdgcn_readlane(__float_as_int(m), 63));

  // ---- q = sum e^2 (same tree shape as validated sum reduce) ----
  float q[4];
  #pragma unroll
  for (int k = 0; k < 4; ++k) {
    float ls = 0.0f;
    #pragma unroll
    for (int e = 0; e < 4; ++e) if (e < NK) {
      float ev = expf(x[k][e] - mx);
      ls = fmaf(ev, ev, ls);
    }
    q[k] = ls;
  }
  #pragma unroll
  for (int k = 0; k < 4; ++k) {
    q[k] += __shfl_xor(q[k], 32);
    q[k] += __shfl_xor(q[k], 16);
    q[k] += __shfl_xor(q[k], 8);
    q[k] += __shfl_xor(q[k], 4);
    q[k] += dpp_f<0x4E>(q[k]);
    q[k] += dpp_f<0xB1>(q[k]);
  }
  float Q = (q[0] + q[1]) + (q[2] + q[3]);

  if (isnan(xg)) xg = -1e9f;
  float pg = expf(xg - mx);
  return pg / sqrtf(Q);
}

// ---------------------------------------------------------------------------
// Kernel 1 (split): 2 waves per row -> 8192 waves = 32 waves/CU (100% cap).
// waveA: accA = c_rel + 0.5*c_hs + 0.5*c_he ; waveB: accB = 0.5*c_ts + 0.5*c_te.
// Partials to d_ws; hungarian combines cost = -(accA+accB) during staging.
// No LDS, no barriers.
// ---------------------------------------------------------------------------
__global__ __launch_bounds__(256, 8) void cost_kernel_split(
    const float* __restrict__ rel,
    const float* __restrict__ hs, const float* __restrict__ he,
    const float* __restrict__ ts, const float* __restrict__ te,
    const int* __restrict__ grel,
    const int* __restrict__ ghs, const int* __restrict__ ghe,
    const int* __restrict__ gts, const int* __restrict__ gte,
    float* __restrict__ wsA, float* __restrict__ wsB)
{
  const int wid   = threadIdx.x >> 6;            // 0..3
  const int lane  = threadIdx.x & 63;
  const int bq    = (blockIdx.x << 1) | (wid >> 1);
  const int b     = bq >> 9;
  const int group = wid & 1;
  const int gl    = (b << 5) + (lane & 31);

  float acc;
  if (group == 0) {
    acc  =        tensor_c<2>(rel + (size_t)bq * 512,  grel[gl], lane);
    acc  = fmaf(0.5f, tensor_c<4>(hs + (size_t)bq * 1024, ghs[gl], lane), acc);
    acc  = fmaf(0.5f, tensor_c<4>(he + (size_t)bq * 1024, ghe[gl], lane), acc);
    if (lane < 32) wsA[(size_t)bq * 32 + lane] = acc;
  } else {
    acc  = 0.5f * tensor_c<4>(ts + (size_t)bq * 1024, gts[gl], lane);
    acc  = fmaf(0.5f, tensor_c<4>(te + (size_t)bq * 1024, gte[gl], lane), acc);
    if (lane < 32) wsB[(size_t)bq * 32 + lane] = acc;
  }
}

// ---------------------------------------------------------------------------
// Kernel 1 (fallback, ws too small): round-5 single-wave version, verbatim
// (validated). Writes cost directly to out.
// ---------------------------------------------------------------------------
__global__ __launch_bounds__(256, 4) void cost_kernel_single(
    const float* __restrict__ rel,
    const float* __restrict__ hs, const float* __restrict__ he,
    const float* __restrict__ ts, const float* __restrict__ te,
    const int* __restrict__ grel,
    const int* __restrict__ ghs, const int* __restrict__ ghe,
    const int* __restrict__ gts, const int* __restrict__ gte,
    float* __restrict__ cost)
{
  const int wid  = threadIdx.x >> 6;
  const int lane = threadIdx.x & 63;
  const int bq   = (blockIdx.x << 2) | wid;
  const int b    = bq >> 9;
  const int gl   = (b << 5) + (lane & 31);
  float acc;
  acc =        tensor_c<2>(rel + (size_t)bq * 512,  grel[gl], lane);
  acc = fmaf(0.5f, tensor_c<4>(hs + (size_t)bq * 1024, ghs[gl], lane), acc);
  acc = fmaf(0.5f, tensor_c<4>(he + (size_t)bq * 1024, ghe[gl], lane), acc);
  acc = fmaf(0.5f, tensor_c<4>(ts + (size_t)bq * 1024, gts[gl], lane), acc);
  acc = fmaf(0.5f, tensor_c<4>(te + (size_t)bq * 1024, gte[gl], lane), acc);
  if (lane < 32) cost[(size_t)bq * 32 + lane] = -acc;
}

// ---------------------------------------------------------------------------
// Kernel 2: collapsed reference-JV replica (derivation validated rounds 3-5);
// all-VALU DPP reduction chain. COMBINE=true additionally fuses
// cost = -(accA+accB) into the staging loop and writes the cost output.
// ---------------------------------------------------------------------------

__device__ __forceinline__ void amin(float& k0, int& m0, float k1, int m1) {
  bool take = (k1 < k0) || (k1 == k0 && m1 < m0);
  k0 = take ? k1 : k0;
  m0 = take ? m1 : m0;
}

template <bool COMBINE>
__global__ __launch_bounds__(64) void hungarian_kernel(
    const float* __restrict__ wsA, const float* __restrict__ wsB,
    float* __restrict__ out)
{
  __shared__ float ct[32][513];  // ct[g][j] = cost[b][j][g]; bank = (g+j)%32
  __shared__ int   rows_s[32];

  const int b    = blockIdx.x;
  const int lane = threadIdx.x;
  const float INFV = __builtin_inff();

  const float4* A4 = reinterpret_cast<const float4*>(wsA) + (size_t)b * 4096;
  const float4* B4 = reinterpret_cast<const float4*>(wsB) + (size_t)b * 4096;
  float4*       O4 = reinterpret_cast<float4*>(out)       + (size_t)b * 4096;

  // stage (+combine) + transpose: coalesced float4, <=2-way banked LDS writes
  #pragma unroll 8
  for (int base = lane; base < 4096; base += 64) {
    float4 val;
    if (COMBINE) {
      float4 a = A4[base];
      float4 c = B4[base];
      val.x = -(a.x + c.x); val.y = -(a.y + c.y);
      val.z = -(a.z + c.z); val.w = -(a.w + c.w);
      O4[base] = val;                    // cost output written here
    } else {
      val = A4[base];                    // wsA aliases out's cost region
    }
    int e0 = base << 2;
    int j  = e0 >> 5;
    int g  = e0 & 31;
    ct[g + 0][j] = val.x;
    ct[g + 1][j] = val.y;
    ct[g + 2][j] = val.z;
    ct[g + 3][j] = val.w;
  }
  __syncthreads();

  unsigned int alive = 0xFFu;
  unsigned int freem = 0xFFu;
  int mtb[8];
  #pragma unroll
  for (int k = 0; k < 8; ++k) mtb[k] = (lane + (k << 6)) << 1;

  float x[8];
  #pragma unroll
  for (int k = 0; k < 8; ++k) x[k] = ct[0][lane + (k << 6)];

  for (int r = 0; r < 32; ++r) {
    float cur[8];
    #pragma unroll
    for (int k = 0; k < 8; ++k) cur[k] = x[k];
    if (r < 31) {
      #pragma unroll
      for (int k = 0; k < 8; ++k) x[k] = ct[r + 1][lane + (k << 6)];
    }

    float ky[8]; int mt[8];
    #pragma unroll
    for (int k = 0; k < 8; ++k) {
      bool a = (alive >> k) & 1u;
      float v = cur[k];
      ky[k] = (a && v < INFV) ? v : INFV;
      mt[k] = mtb[k] | (int)((freem >> k) & 1u);
    }
    amin(ky[0], mt[0], ky[1], mt[1]); amin(ky[2], mt[2], ky[3], mt[3]);
    amin(ky[4], mt[4], ky[5], mt[5]); amin(ky[6], mt[6], ky[7], mt[7]);
    amin(ky[0], mt[0], ky[2], mt[2]); amin(ky[4], mt[4], ky[6], mt[6]);
    amin(ky[0], mt[0], ky[4], mt[4]);
    float bkey = ky[0]; int bmeta = mt[0];

    unsigned int cm = alive & freem;
    int bfj = cm ? (lane + (__builtin_ctz(cm) << 6)) : 0x7FFFFFFF;

    #define BF_STEP(OPK, OPM, OPF)                                           \
      { float ok = (OPK); int om = (OPM); int of = (OPF);                    \
        bool take = (ok < bkey) || (ok == bkey && om < bmeta);               \
        bkey = take ? ok : bkey; bmeta = take ? om : bmeta;                  \
        bfj = min(bfj, of); }

    BF_STEP(dpp_f<0xB1>(bkey),  dpp_i<0xB1>(bmeta),  dpp_i<0xB1>(bfj))
    BF_STEP(dpp_f<0x4E>(bkey),  dpp_i<0x4E>(bmeta),  dpp_i<0x4E>(bfj))
    BF_STEP(dpp_f<0x141>(bkey), dpp_i<0x141>(bmeta), dpp_i<0x141>(bfj))
    BF_STEP(dpp_f<0x140>(bkey), dpp_i<0x140>(bmeta), dpp_i<0x140>(bfj))
    BF_STEP(dpp_f<0x142>(bkey), dpp_i<0x142>(bmeta), dpp_i<0x142>(bfj))
    BF_STEP(dpp_f<0x143>(bkey), dpp_i<0x143>(bmeta), dpp_i<0x143>(bfj))
    #undef BF_STEP

    const int smeta = __builtin_amdgcn_readlane(bmeta, 63);
    const int sfj   = __builtin_amdgcn_readlane(bfj, 63);
    const int j1    = smeta >> 1;

    int jwin;
    if (smeta & 1) {
      jwin = j1;
    } else {
      if (lane == (j1 & 63)) alive &= ~(1u << (j1 >> 6));
      int d = sfj - lane;
      int K = d > 0 ? ((d + 63) >> 6) : 0;
      if (K > 8) K = 8;
      alive &= ~((1u << K) - 1u);
      jwin = sfj;
    }
    if (lane == (jwin & 63)) freem &= ~(1u << (jwin >> 6));
    if (lane == 0) rows_s[r] = jwin;
  }
  __syncthreads();

  if (lane < 32) {
    int rv = rows_s[lane];
    int rank = 0;
    #pragma unroll
    for (int g = 0; g < 32; ++g) rank += (rows_s[g] < rv) ? 1 : 0;
    out[131072 +       b * 32 + rank] = (float)rv;
    out[131072 + 256 + b * 32 + rank] = (float)lane;
  }
}

// ---------------------------------------------------------------------------

extern "C" void kernel_launch(void* const* d_in, const int* in_sizes, int n_in,
                              void* d_out, int out_size, void* d_ws, size_t ws_size,
                              hipStream_t stream) {
  const float* rel = (const float*)d_in[0];
  const float* hs  = (const float*)d_in[1];
  const float* he  = (const float*)d_in[2];
  const float* ts  = (const float*)d_in[3];
  const float* te  = (const float*)d_in[4];
  const int* grel = (const int*)d_in[5];
  const int* ghs  = (const int*)d_in[6];
  const int* ghe  = (const int*)d_in[7];
  const int* gts  = (const int*)d_in[8];
  const int* gte  = (const int*)d_in[9];

  float* out = (float*)d_out;

  if (ws_size >= 262144 * sizeof(float)) {
    float* wsA = (float*)d_ws;
    float* wsB = wsA + 131072;
    cost_kernel_split<<<2048, 256, 0, stream>>>(rel, hs, he, ts, te,
                                                grel, ghs, ghe, gts, gte,
                                                wsA, wsB);
    hungarian_kernel<true><<<8, 64, 0, stream>>>(wsA, wsB, out);
  } else {
    cost_kernel_single<<<1024, 256, 0, stream>>>(rel, hs, he, ts, te,
                                                 grel, ghs, ghe, gts, gte, out);
    hungarian_kernel<false><<<8, 64, 0, stream>>>(out, out, out);
  }
}

// Round 7
// 33.603 us; speedup vs baseline: 8.0634x; 1.6401x over previous
//
#include <hip/hip_runtime.h>
#include <hip/hip_bf16.h>
#include <math.h>

// ---------------------------------------------------------------------------
// DPP helpers. Controls: 0xB1 quad_perm(1,0,3,2)=xor1 (exact), 0x4E
// quad_perm(2,3,0,1)=xor2 (exact), 0x141 row_half_mirror=xor7 (exact),
// 0x140 row_mirror=xor15 (exact), 0x142 row_bcast15, 0x143 row_bcast31.
// Reduce pattern (xor1,xor2,xor7,xor15,bcast15,bcast31 -> lane63 -> readlane)
// validated bit-exact in rounds 5-6.
// ---------------------------------------------------------------------------
template <int CTRL>
__device__ __forceinline__ int dpp_i(int x) {
  return __builtin_amdgcn_update_dpp(0, x, CTRL, 0xF, 0xF, true);
}
template <int CTRL>
__device__ __forceinline__ float dpp_f(float x) {
  return __int_as_float(__builtin_amdgcn_update_dpp(0, __float_as_int(x), CTRL, 0xF, 0xF, true));
}

// ---------------------------------------------------------------------------
// Per-tensor normalized-softmax gather: c = e_g / sqrt(sum e^2)  (S cancels
// exactly; validated rounds 6: absmax 0.0). Reduction trees unchanged.
// ---------------------------------------------------------------------------
template <int NK>
__device__ __forceinline__ float tensor_c(const float* __restrict__ row,
                                          int idx, int lane) {
  float x[4][4];
  float xg = row[idx];
  if (NK == 4) {
    #pragma unroll
    for (int k = 0; k < 4; ++k) {
      float4 v4 = *reinterpret_cast<const float4*>(row + (k << 8) + lane * 4);
      x[k][0] = v4.x; x[k][1] = v4.y; x[k][2] = v4.z; x[k][3] = v4.w;
    }
  } else {
    #pragma unroll
    for (int k = 0; k < 4; ++k) {
      float2 v2 = *reinterpret_cast<const float2*>(row + (k << 7) + lane * 2);
      x[k][0] = v2.x; x[k][1] = v2.y; x[k][2] = 0.0f; x[k][3] = 0.0f;
    }
  }

  float m = -INFINITY;
  #pragma unroll
  for (int k = 0; k < 4; ++k) {
    #pragma unroll
    for (int e = 0; e < 4; ++e) if (e < NK) {
      if (isnan(x[k][e])) x[k][e] = -1e9f;
      m = fmaxf(m, x[k][e]);
    }
  }
  m = fmaxf(m, dpp_f<0xB1>(m));
  m = fmaxf(m, dpp_f<0x4E>(m));
  m = fmaxf(m, dpp_f<0x141>(m));
  m = fmaxf(m, dpp_f<0x140>(m));
  m = fmaxf(m, dpp_f<0x142>(m));
  m = fmaxf(m, dpp_f<0x143>(m));
  float mx = __int_as_float(__builtin_amdgcn_readlane(__float_as_int(m), 63));

  float q[4];
  #pragma unroll
  for (int k = 0; k < 4; ++k) {
    float ls = 0.0f;
    #pragma unroll
    for (int e = 0; e < 4; ++e) if (e < NK) {
      float ev = expf(x[k][e] - mx);
      ls = fmaf(ev, ev, ls);
    }
    q[k] = ls;
  }
  #pragma unroll
  for (int k = 0; k < 4; ++k) {
    q[k] += __shfl_xor(q[k], 32);
    q[k] += __shfl_xor(q[k], 16);
    q[k] += __shfl_xor(q[k], 8);
    q[k] += __shfl_xor(q[k], 4);
    q[k] += dpp_f<0x4E>(q[k]);
    q[k] += dpp_f<0xB1>(q[k]);
  }
  float Q = (q[0] + q[1]) + (q[2] + q[3]);

  if (isnan(xg)) xg = -1e9f;
  float pg = expf(xg - mx);
  return pg / sqrtf(Q);
}

// ---------------------------------------------------------------------------
// Kernel 1 (fused): 2 rows/block, 2 waves/row (A: rel+0.5hs+0.5he,
// B: 0.5ts+0.5te). B's partial goes through LDS; A combines -(accA+accB)
// (same arithmetic order as validated round 6) and writes BOTH the cost
// output AND a transposed copy T[b][g][q] into d_ws so hungarian can stage
// linearly with zero transpose work.
// ---------------------------------------------------------------------------
__global__ __launch_bounds__(256, 8) void cost_kernel_fused(
    const float* __restrict__ rel,
    const float* __restrict__ hs, const float* __restrict__ he,
    const float* __restrict__ ts, const float* __restrict__ te,
    const int* __restrict__ grel,
    const int* __restrict__ ghs, const int* __restrict__ ghe,
    const int* __restrict__ gts, const int* __restrict__ gte,
    float* __restrict__ cost, float* __restrict__ T)
{
  __shared__ float smB[2][32];
  const int wid   = threadIdx.x >> 6;
  const int lane  = threadIdx.x & 63;
  const int pair  = wid >> 1;                    // row within block: 0..1
  const int group = wid & 1;                     // 0 = A, 1 = B
  const int bq    = (blockIdx.x << 1) | pair;
  const int b     = bq >> 9;
  const int gl    = (b << 5) + (lane & 31);

  float accA = 0.0f;
  if (group == 0) {
    accA =        tensor_c<2>(rel + (size_t)bq * 512,  grel[gl], lane);
    accA = fmaf(0.5f, tensor_c<4>(hs + (size_t)bq * 1024, ghs[gl], lane), accA);
    accA = fmaf(0.5f, tensor_c<4>(he + (size_t)bq * 1024, ghe[gl], lane), accA);
  } else {
    float accB = 0.5f * tensor_c<4>(ts + (size_t)bq * 1024, gts[gl], lane);
    accB = fmaf(0.5f, tensor_c<4>(te + (size_t)bq * 1024, gte[gl], lane), accB);
    if (lane < 32) smB[pair][lane] = accB;
  }
  __syncthreads();
  if (group == 0 && lane < 32) {
    float tot = -(accA + smB[pair][lane]);       // same expr as round 6
    cost[(size_t)bq * 32 + lane] = tot;
    T[(size_t)b * 16384 + lane * 512 + (bq & 511)] = tot;
  }
}

// Fallback (ws too small): validated round-5/6 single-wave cost to out.
__global__ __launch_bounds__(256, 4) void cost_kernel_single(
    const float* __restrict__ rel,
    const float* __restrict__ hs, const float* __restrict__ he,
    const float* __restrict__ ts, const float* __restrict__ te,
    const int* __restrict__ grel,
    const int* __restrict__ ghs, const int* __restrict__ ghe,
    const int* __restrict__ gts, const int* __restrict__ gte,
    float* __restrict__ cost)
{
  const int wid  = threadIdx.x >> 6;
  const int lane = threadIdx.x & 63;
  const int bq   = (blockIdx.x << 2) | wid;
  const int b    = bq >> 9;
  const int gl   = (b << 5) + (lane & 31);
  float acc;
  acc =        tensor_c<2>(rel + (size_t)bq * 512,  grel[gl], lane);
  acc = fmaf(0.5f, tensor_c<4>(hs + (size_t)bq * 1024, ghs[gl], lane), acc);
  acc = fmaf(0.5f, tensor_c<4>(he + (size_t)bq * 1024, ghe[gl], lane), acc);
  acc = fmaf(0.5f, tensor_c<4>(ts + (size_t)bq * 1024, gts[gl], lane), acc);
  acc = fmaf(0.5f, tensor_c<4>(te + (size_t)bq * 1024, gte[gl], lane), acc);
  if (lane < 32) cost[(size_t)bq * 32 + lane] = -acc;
}

// ---------------------------------------------------------------------------
// Kernel 2: collapsed reference-JV replica (derivation validated r3-r6).
// Round-7 turn loop: value-only f32 min reduce (6 single-instr DPP steps) +
// equality locate. Key values are IDENTICAL to the validated meta scheme
// (ky = cur + amask, amask in {0,+INF}; NaN/INF folded at load), and the
// free flag never influenced the argmin order (meta=(j<<1)|free, j dominant)
// — it only selected the branch, which we now test directly on freem.
// Tie cases go through an exact min-j fallback (same j ordering).
// ---------------------------------------------------------------------------
template <bool PRETRANS>
__global__ __launch_bounds__(64) void hungarian_kernel(
    const float* __restrict__ src,   // PRETRANS ? T[b][g][j] : cost[b][j][g]
    float* __restrict__ out)
{
  __shared__ __align__(16) float ct[32 * 512];   // ct[g*512+j]; reads 2-way ok
  __shared__ int rows_s[32];

  const int b    = blockIdx.x;
  const int lane = threadIdx.x;
  const float INFV = __builtin_inff();

  if (PRETRANS) {
    // linear 64KB copy: coalesced float4 loads -> ds_write_b128, no math
    const float4* T4 = reinterpret_cast<const float4*>(src + (size_t)b * 16384);
    #pragma unroll 16
    for (int it = lane; it < 4096; it += 64) {
      float4 v = T4[it];
      *reinterpret_cast<float4*>(ct + (it << 2)) = v;
    }
  } else {
    const float4* C4 = reinterpret_cast<const float4*>(src + (size_t)b * 16384);
    #pragma unroll 8
    for (int base = lane; base < 4096; base += 64) {
      float4 v = C4[base];
      int e0 = base << 2;
      int j  = e0 >> 5;
      int g  = e0 & 31;
      ct[(g + 0) * 512 + j] = v.x;
      ct[(g + 1) * 512 + j] = v.y;
      ct[(g + 2) * 512 + j] = v.z;
      ct[(g + 3) * 512 + j] = v.w;
    }
  }
  __syncthreads();

  unsigned alive = 0xFFu;            // bit k: column j=lane+64k has v[j]==0
  unsigned freem = 0xFFu;            // bit k: column j=lane+64k unassigned
  float amask[8];
  int   jk[8];
  #pragma unroll
  for (int k = 0; k < 8; ++k) { amask[k] = 0.0f; jk[k] = lane + (k << 6); }

  // row 0, NaN/+INF folded (fmin(NaN,INF)=INF; fmin(x,INF)=x)
  float cur[8];
  #pragma unroll
  for (int k = 0; k < 8; ++k) cur[k] = fminf(ct[lane + (k << 6)], INFV);

  for (int r = 0; r < 32; ++r) {
    // ---- keys + local min (tree) ----
    float ky[8];
    #pragma unroll
    for (int k = 0; k < 8; ++k) ky[k] = cur[k] + amask[k];   // dead -> +INF
    float mm = fminf(fminf(fminf(ky[0], ky[1]), fminf(ky[2], ky[3])),
                     fminf(fminf(ky[4], ky[5]), fminf(ky[6], ky[7])));

    // ---- 6-step value-only DPP min (validated shape) ----
    mm = fminf(mm, dpp_f<0xB1>(mm));
    mm = fminf(mm, dpp_f<0x4E>(mm));
    mm = fminf(mm, dpp_f<0x141>(mm));
    mm = fminf(mm, dpp_f<0x140>(mm));
    mm = fminf(mm, dpp_f<0x142>(mm));
    mm = fminf(mm, dpp_f<0x143>(mm));
    const float s_m = __int_as_float(
        __builtin_amdgcn_readlane(__float_as_int(mm), 63));

    // prefetch next row (consumed after this turn's scalar work)
    float xn[8];
    if (r < 31) {
      #pragma unroll
      for (int k = 0; k < 8; ++k) xn[k] = ct[((r + 1) << 9) + lane + (k << 6)];
    }

    // ---- locate j1 = min j with ky==m (exact reference tie-break) ----
    int jl[8];
    #pragma unroll
    for (int k = 0; k < 8; ++k) jl[k] = (ky[k] == s_m) ? jk[k] : 0x7FFFFFFF;
    int j0 = min(min(min(jl[0], jl[1]), min(jl[2], jl[3])),
                 min(min(jl[4], jl[5]), min(jl[6], jl[7])));
    unsigned long long hit = __ballot(j0 != 0x7FFFFFFF);
    int j1;
    if (__popcll(hit) == 1) {                    // unique min value (typical)
      j1 = __builtin_amdgcn_readlane(j0, (int)__builtin_ctzll(hit));
    } else {                                     // exact min-j reduce (rare)
      int t = j0;
      t = min(t, dpp_i<0xB1>(t));
      t = min(t, dpp_i<0x4E>(t));
      t = min(t, dpp_i<0x141>(t));
      t = min(t, dpp_i<0x140>(t));
      t = min(t, dpp_i<0x142>(t));
      t = min(t, dpp_i<0x143>(t));
      j1 = __builtin_amdgcn_readlane(t, 63);
    }

    // ---- free test, then assign / kill-walk (semantics validated r3-r6) ----
    const int s_kq = j1 >> 6, s_ow = j1 & 63;
    unsigned long long fb = __ballot(lane == s_ow && ((freem >> s_kq) & 1u));
    int jwin;
    if (fb) {                                    // j1 free: assign, stays alive
      jwin = j1;
    } else {                                     // kill j1; walk to jF
      if (lane == s_ow) alive &= ~(1u << s_kq);
      #pragma unroll
      for (int k = 0; k < 8; ++k)
        amask[k] = (k == s_kq && lane == s_ow) ? INFV : amask[k];
      unsigned cm = alive & freem;
      int jF = 0;
      #pragma unroll
      for (int k = 0; k < 8; ++k) {              // expected exit at k=0/1
        unsigned long long bk = __ballot((cm >> k) & 1u);
        if (bk) { jF = (k << 6) + (int)__builtin_ctzll(bk); break; }
      }
      int d = jF - lane;                         // kill alive j < jF
      int K = d > 0 ? ((d + 63) >> 6) : 0;
      if (K > 8) K = 8;
      #pragma unroll
      for (int k = 0; k < 8; ++k) amask[k] = (k < K) ? INFV : amask[k];
      alive &= ~((1u << K) - 1u);
      jwin = jF;                                 // jF stays alive
    }
    if (lane == (jwin & 63)) freem &= ~(1u << (jwin >> 6));
    if (lane == 0) rows_s[r] = jwin;

    if (r < 31) {
      #pragma unroll
      for (int k = 0; k < 8; ++k) cur[k] = fminf(xn[k], INFV);
    }
  }
  __syncthreads();

  // wave-parallel epilogue: rank sort (values distinct)
  if (lane < 32) {
    int rv = rows_s[lane];
    int rank = 0;
    #pragma unroll
    for (int g = 0; g < 32; ++g) rank += (rows_s[g] < rv) ? 1 : 0;
    out[131072 +       b * 32 + rank] = (float)rv;
    out[131072 + 256 + b * 32 + rank] = (float)lane;
  }
}

// ---------------------------------------------------------------------------

extern "C" void kernel_launch(void* const* d_in, const int* in_sizes, int n_in,
                              void* d_out, int out_size, void* d_ws, size_t ws_size,
                              hipStream_t stream) {
  const float* rel = (const float*)d_in[0];
  const float* hs  = (const float*)d_in[1];
  const float* he  = (const float*)d_in[2];
  const float* ts  = (const float*)d_in[3];
  const float* te  = (const float*)d_in[4];
  const int* grel = (const int*)d_in[5];
  const int* ghs  = (const int*)d_in[6];
  const int* ghe  = (const int*)d_in[7];
  const int* gts  = (const int*)d_in[8];
  const int* gte  = (const int*)d_in[9];

  float* out = (float*)d_out;

  if (ws_size >= 131072 * sizeof(float)) {
    float* T = (float*)d_ws;                     // [8][32][512] transposed cost
    cost_kernel_fused<<<2048, 256, 0, stream>>>(rel, hs, he, ts, te,
                                                grel, ghs, ghe, gts, gte,
                                                out, T);
    hungarian_kernel<true><<<8, 64, 0, stream>>>(T, out);
  } else {
    cost_kernel_single<<<1024, 256, 0, stream>>>(rel, hs, he, ts, te,
                                                 grel, ghs, ghe, gts, gte, out);
    hungarian_kernel<false><<<8, 64, 0, stream>>>(out, out);
  }
}